// Round 1
// baseline (627.232 us; speedup 1.0000x reference)
//
#include <hip/hip_runtime.h>
#include <cstddef>
#include <cstdint>

#define B_ 16
#define H_ 16
#define NQ 8
#define D_ 128
#define E_ 2048
#define F3 6144
#define KVP 4096
#define KVT 4104
#define SCALE 0.08838834764831843f
#define NCHUNK 8
#define CHUNK 512
#define SUBR 32
#define NSUB 16
#define PARTSZ 1040  // 8 m + 8 l + 8*128 acc

// ---------------- GEMM: C[M][F] = X[M][K] * W[F][K]^T (fp32) ----------------
template <int BM, int BN>
__global__ __launch_bounds__(256) void gemm_xwt(const float* __restrict__ X,
                                                const float* __restrict__ W,
                                                float* __restrict__ C,
                                                int K, int Fdim) {
  constexpr int BK = 32;
  constexpr int RM = BM / 16;
  constexpr int RN = BN / 16;
  __shared__ float xs[BK][BM + 4];   // [k][m], pad keeps 16B alignment + banks spread
  __shared__ float wss[BK][BN + 4];  // [k][f]
  const int t = threadIdx.x;
  const int tm = t >> 4, tn = t & 15;
  const int m0 = blockIdx.y * BM, f0 = blockIdx.x * BN;
  float acc[RM][RN];
#pragma unroll
  for (int i = 0; i < RM; ++i)
#pragma unroll
    for (int j = 0; j < RN; ++j) acc[i][j] = 0.f;

  for (int kk = 0; kk < K; kk += BK) {
#pragma unroll
    for (int i = 0; i < (BM * BK) / 1024; ++i) {
      int j = t + i * 256;
      int r = j >> 3;
      int c = (j & 7) << 2;
      float4 v = *reinterpret_cast<const float4*>(&X[(size_t)(m0 + r) * K + kk + c]);
      xs[c + 0][r] = v.x; xs[c + 1][r] = v.y; xs[c + 2][r] = v.z; xs[c + 3][r] = v.w;
    }
#pragma unroll
    for (int i = 0; i < (BN * BK) / 1024; ++i) {
      int j = t + i * 256;
      int r = j >> 3;
      int c = (j & 7) << 2;
      float4 v = *reinterpret_cast<const float4*>(&W[(size_t)(f0 + r) * K + kk + c]);
      wss[c + 0][r] = v.x; wss[c + 1][r] = v.y; wss[c + 2][r] = v.z; wss[c + 3][r] = v.w;
    }
    __syncthreads();
#pragma unroll
    for (int k = 0; k < BK; ++k) {
      float xv[RM], wv[RN];
      if constexpr (RM == 4) {
        *reinterpret_cast<float4*>(xv) = *reinterpret_cast<const float4*>(&xs[k][tm * 4]);
      } else {
        *reinterpret_cast<float2*>(xv) = *reinterpret_cast<const float2*>(&xs[k][tm * 2]);
      }
      if constexpr (RN == 4) {
        *reinterpret_cast<float4*>(wv) = *reinterpret_cast<const float4*>(&wss[k][tn * 4]);
      } else {
        *reinterpret_cast<float2*>(wv) = *reinterpret_cast<const float2*>(&wss[k][tn * 2]);
      }
#pragma unroll
      for (int i = 0; i < RM; ++i)
#pragma unroll
        for (int j = 0; j < RN; ++j) acc[i][j] += xv[i] * wv[j];
    }
    __syncthreads();
  }
#pragma unroll
  for (int i = 0; i < RM; ++i) {
    float* cp = &C[(size_t)(m0 + tm * RM + i) * Fdim + f0 + tn * RN];
    if constexpr (RN == 4) {
      float4 v = make_float4(acc[i][0], acc[i][1], acc[i][2], acc[i][3]);
      *reinterpret_cast<float4*>(cp) = v;
    } else {
      float2 v = make_float2(acc[i][0], acc[i][1]);
      *reinterpret_cast<float2*>(cp) = v;
    }
  }
}

// ------- Fused KV-cache copy + flash-attention partials over past chunks -------
// grid: (NCHUNK, H, B), 256 threads.
__global__ __launch_bounds__(256) void attn_partial(
    const float* __restrict__ past_k, const float* __restrict__ past_v,
    const float* __restrict__ qkv, float* __restrict__ out_k,
    float* __restrict__ out_v, float* __restrict__ part) {
  const int t = threadIdx.x;
  const int c = blockIdx.x, h = blockIdx.y, b = blockIdx.z;
  const int bh = b * H_ + h;

  __shared__ float q_lds[NQ * D_];     // linear
  __shared__ float k_lds[SUBR * D_];   // f4-column XOR-swizzled: slot g^(row&7)
  __shared__ float v_lds[SUBR * D_];   // same swizzle
  __shared__ float p_lds[SUBR * 12];   // [row][qi] padded to 12 (f4-friendly)
  __shared__ float cm_lds[NQ], cs_lds[NQ];
  __shared__ float m_lds[2][NQ], l_lds[2][NQ];  // ping-pong running max / denom

  {
    int n = t >> 5, g = t & 31;
    *reinterpret_cast<float4*>(&q_lds[n * D_ + g * 4]) =
        *reinterpret_cast<const float4*>(&qkv[(size_t)(b * NQ + n) * F3 + h * D_ + g * 4]);
  }
  if (t < NQ) { m_lds[0][t] = -1e30f; l_lds[0][t] = 0.f; }

  const int srow = t & 31, sqi = t >> 5;   // score-phase role
  const int qg = t >> 7, dcol = t & 127;   // PV-phase role
  const int pvq = dcol >> 2, pve = dcol & 3;
  float acc[4] = {0.f, 0.f, 0.f, 0.f};

  const float* gk = past_k + ((size_t)bh * KVP + (size_t)c * CHUNK) * D_;
  const float* gv = past_v + ((size_t)bh * KVP + (size_t)c * CHUNK) * D_;
  float* ok = out_k + ((size_t)bh * KVT + (size_t)c * CHUNK) * D_;
  float* ov = out_v + ((size_t)bh * KVT + (size_t)c * CHUNK) * D_;

  __syncthreads();  // q_lds + m/l init visible

  for (int sub = 0; sub < NSUB; ++sub) {
    const int cur = sub & 1, nxt = cur ^ 1;
    const size_t off = (size_t)sub * SUBR * D_;
    // ---- stage: global -> reg -> {output cache, swizzled LDS} ----
#pragma unroll
    for (int i = 0; i < 4; ++i) {
      int j = t + i * 256;              // f4 index within 32x128 tile
      int row = j >> 5, g = j & 31;
      size_t ga = off + (size_t)row * D_ + g * 4;
      float4 kv = *reinterpret_cast<const float4*>(&gk[ga]);
      float4 vv = *reinterpret_cast<const float4*>(&gv[ga]);
      *reinterpret_cast<float4*>(&ok[ga]) = kv;
      *reinterpret_cast<float4*>(&ov[ga]) = vv;
      int gs = (g ^ (row & 7)) << 2;
      *reinterpret_cast<float4*>(&k_lds[row * D_ + gs]) = kv;
      *reinterpret_cast<float4*>(&v_lds[row * D_ + gs]) = vv;
    }
    __syncthreads();  // B1: LDS tile ready
    // ---- scores: s[srow][sqi] = scale * q[sqi] . k[srow] ----
    float s = 0.f;
    {
      const int sw = srow & 7;
      const float4* k4 = reinterpret_cast<const float4*>(k_lds);
      const float4* q4 = reinterpret_cast<const float4*>(&q_lds[sqi * D_]);
#pragma unroll
      for (int g = 0; g < 32; ++g) {
        float4 kv = k4[srow * 32 + (g ^ sw)];
        float4 qv = q4[g];
        s += kv.x * qv.x + kv.y * qv.y + kv.z * qv.z + kv.w * qv.w;
      }
    }
    s *= SCALE;
    float cmax = s;
#pragma unroll
    for (int o = 16; o > 0; o >>= 1) cmax = fmaxf(cmax, __shfl_xor(cmax, o));
    float mo = m_lds[cur][sqi];
    float mn = fmaxf(mo, cmax);
    float p = __expf(s - mn);
    float psum = p;
#pragma unroll
    for (int o = 16; o > 0; o >>= 1) psum += __shfl_xor(psum, o);
    p_lds[srow * 12 + sqi] = p;
    if (srow == 0) { cm_lds[sqi] = cmax; cs_lds[sqi] = psum; }
    __syncthreads();  // B2: p/cm/cs ready
    // ---- PV accumulate (threads own acc[qi = qg*4+j][dcol]) ----
#pragma unroll
    for (int jq = 0; jq < 4; ++jq) {
      int qi = qg * 4 + jq;
      float mo2 = m_lds[cur][qi];
      float mn2 = fmaxf(mo2, cm_lds[qi]);
      acc[jq] *= __expf(mo2 - mn2);
    }
#pragma unroll
    for (int r = 0; r < SUBR; ++r) {
      float4 p4 = *reinterpret_cast<const float4*>(&p_lds[r * 12 + qg * 4]);
      float vv = v_lds[r * D_ + (((pvq ^ (r & 7)) << 2) | pve)];
      acc[0] += p4.x * vv; acc[1] += p4.y * vv;
      acc[2] += p4.z * vv; acc[3] += p4.w * vv;
    }
    if (t < NQ) {
      float mo2 = m_lds[cur][t];
      float mn2 = fmaxf(mo2, cm_lds[t]);
      l_lds[nxt][t] = l_lds[cur][t] * __expf(mo2 - mn2) + cs_lds[t];
      m_lds[nxt][t] = mn2;
    }
    __syncthreads();  // B3: PV done + m/l updated before LDS overwrite
  }
  // ---- emit partials: [m(8) | l(8) | acc(8x128)] ----
  float* pb = part + ((size_t)bh * NCHUNK + c) * PARTSZ;
  if (t < NQ) { pb[t] = m_lds[0][t]; pb[8 + t] = l_lds[0][t]; }  // NSUB even -> slot 0
#pragma unroll
  for (int jq = 0; jq < 4; ++jq)
    pb[16 + (size_t)(qg * 4 + jq) * D_ + dcol] = acc[jq];
}

// ------- new-token chunk + combine partials -> attention output (pre-proj) -------
// grid: (H, B), 256 threads.
__global__ __launch_bounds__(256) void attn_combine(
    const float* __restrict__ qkv, const float* __restrict__ part,
    float* __restrict__ out_k, float* __restrict__ out_v,
    float* __restrict__ attn) {
  const int t = threadIdx.x;
  const int h = blockIdx.x, b = blockIdx.y;
  const int bh = b * H_ + h;
  __shared__ float q_lds[NQ * 132];
  __shared__ float kn_lds[NQ * 132];
  __shared__ float vn_lds[NQ * 132];
  __shared__ float p9[NQ * 12];
  __shared__ float m9_lds[NQ], s9_lds[NQ];
  {
    int n = t >> 5, g = t & 31;
    const float* src = &qkv[(size_t)(b * NQ + n) * F3 + h * D_ + g * 4];
    float4 qv = *reinterpret_cast<const float4*>(src);
    float4 kv = *reinterpret_cast<const float4*>(src + E_);
    float4 vv = *reinterpret_cast<const float4*>(src + 2 * E_);
    *reinterpret_cast<float4*>(&q_lds[n * 132 + g * 4]) = qv;
    *reinterpret_cast<float4*>(&kn_lds[n * 132 + g * 4]) = kv;
    *reinterpret_cast<float4*>(&vn_lds[n * 132 + g * 4]) = vv;
    // append new rows to the KV cache tail
    *reinterpret_cast<float4*>(&out_k[((size_t)bh * KVT + KVP + n) * D_ + g * 4]) = kv;
    *reinterpret_cast<float4*>(&out_v[((size_t)bh * KVT + KVP + n) * D_ + g * 4]) = vv;
  }
  __syncthreads();
  if (t < 64) {
    int nq = t >> 3, nk = t & 7;
    float s = 0.f;
#pragma unroll
    for (int g = 0; g < 32; ++g) {
      float4 qv = *reinterpret_cast<const float4*>(&q_lds[nq * 132 + g * 4]);
      float4 kv = *reinterpret_cast<const float4*>(&kn_lds[nk * 132 + g * 4]);
      s += qv.x * kv.x + qv.y * kv.y + qv.z * kv.z + qv.w * kv.w;
    }
    s *= SCALE;
    float mx = s;
#pragma unroll
    for (int o = 4; o > 0; o >>= 1) mx = fmaxf(mx, __shfl_xor(mx, o));
    float p = __expf(s - mx);
    float sm = p;
#pragma unroll
    for (int o = 4; o > 0; o >>= 1) sm += __shfl_xor(sm, o);
    p9[nk * 12 + nq] = p;
    if (nk == 0) { m9_lds[nq] = mx; s9_lds[nq] = sm; }
  }
  __syncthreads();
  const int qg = t >> 7, dcol = t & 127;
  const float* pb = part + (size_t)bh * NCHUNK * PARTSZ;
#pragma unroll
  for (int jq = 0; jq < 4; ++jq) {
    int qi = qg * 4 + jq;
    float M = m9_lds[qi];
#pragma unroll
    for (int c = 0; c < NCHUNK; ++c) M = fmaxf(M, pb[(size_t)c * PARTSZ + qi]);
    float num = 0.f, den = 0.f;
#pragma unroll
    for (int c = 0; c < NCHUNK; ++c) {
      const float* pc = pb + (size_t)c * PARTSZ;
      float w = __expf(pc[qi] - M);
      den += w * pc[8 + qi];
      num += w * pc[16 + (size_t)qi * D_ + dcol];
    }
    float acc9 = 0.f;
#pragma unroll
    for (int r = 0; r < NQ; ++r) acc9 += p9[r * 12 + qi] * vn_lds[r * 132 + dcol];
    float w9 = __expf(m9_lds[qi] - M);
    num += w9 * acc9;
    den += w9 * s9_lds[qi];
    attn[((size_t)(b * NQ + qi)) * E_ + h * D_ + dcol] = num / den;
  }
}

extern "C" void kernel_launch(void* const* d_in, const int* in_sizes, int n_in,
                              void* d_out, int out_size, void* d_ws, size_t ws_size,
                              hipStream_t stream) {
  const float* x      = (const float*)d_in[0];
  const float* past_k = (const float*)d_in[1];
  const float* past_v = (const float*)d_in[2];
  const float* W_qkv  = (const float*)d_in[3];
  const float* W_out  = (const float*)d_in[4];

  float* out   = (float*)d_out;
  float* out_k = out + (size_t)B_ * NQ * E_;            // 262144
  float* out_v = out_k + (size_t)B_ * H_ * KVT * D_;    // +134479872

  float* ws   = (float*)d_ws;
  float* qkv  = ws;                                      // 786432 floats
  float* part = qkv + (size_t)B_ * NQ * F3;              // 2129920 floats
  float* attn = part + (size_t)B_ * H_ * NCHUNK * PARTSZ;// 262144 floats

  // 1) fused QKV projection
  gemm_xwt<64, 64><<<dim3(F3 / 64, 128 / 64), 256, 0, stream>>>(x, W_qkv, qkv, E_, F3);
  // 2) fused KV-cache copy + flash partials over past chunks
  attn_partial<<<dim3(NCHUNK, H_, B_), 256, 0, stream>>>(past_k, past_v, qkv, out_k, out_v, part);
  // 3) new-token chunk + combine -> attention output (pre out-proj)
  attn_combine<<<dim3(H_, B_), 256, 0, stream>>>(qkv, part, out_k, out_v, attn);
  // 4) output projection
  gemm_xwt<32, 32><<<dim3(E_ / 32, 128 / 32), 256, 0, stream>>>(attn, W_out, out, E_, E_);
}